// Round 1
// baseline (21.577 us; speedup 1.0000x reference)
//
#include <hip/hip_runtime.h>

// WeightedAverage: 3x3 patch softmax-weighted average over RGB, weights from
// luminance differences, zero padding (pad taps join softmax denom with L=0).
// x: [N,3,512,512] f32, out: same.

#define HH 512
#define WW 512
#define HWSZ (HH * WW)

__global__ __launch_bounds__(256) void wavg_kernel(const float* __restrict__ x,
                                                   float* __restrict__ out,
                                                   int total /* N*H*W */) {
    int idx = blockIdx.x * 256 + threadIdx.x;
    if (idx >= total) return;

    int n   = idx >> 18;          // / (512*512)
    int rem = idx & (HWSZ - 1);
    int h   = rem >> 9;
    int w   = rem & (WW - 1);

    const float* Rp = x + (size_t)n * 3 * HWSZ;
    const float* Gp = Rp + HWSZ;
    const float* Bp = Gp + HWSZ;

    float rc = Rp[rem], gc = Gp[rem], bc = Bp[rem];
    float lc = 0.2126f * rc + 0.7152f * gc + 0.0722f * bc;

    float sw = 0.f, sr = 0.f, sg = 0.f, sb = 0.f;

#pragma unroll
    for (int dy = -1; dy <= 1; ++dy) {
#pragma unroll
        for (int dx = -1; dx <= 1; ++dx) {
            int hh = h + dy, ww = w + dx;
            bool inb = ((unsigned)hh < HH) & ((unsigned)ww < WW);
            int i2 = (hh << 9) + ww;
            float rn = 0.f, gn = 0.f, bn = 0.f;
            if (inb) {
                rn = Rp[i2];
                gn = Gp[i2];
                bn = Bp[i2];
            }
            float ln = 0.2126f * rn + 0.7152f * gn + 0.0722f * bn;
            float d  = ln - lc;
            float wt = __expf(-d * d);   // exponent in [-1, 0]; matches softmax
            sw += wt;
            sr += wt * rn;
            sg += wt * gn;
            sb += wt * bn;
        }
    }

    float inv = __builtin_amdgcn_rcpf(sw);  // sw in [1, 9]; approx rcp is plenty
    float* Orp = out + (size_t)n * 3 * HWSZ;
    Orp[rem]            = sr * inv;
    Orp[rem + HWSZ]     = sg * inv;
    Orp[rem + 2 * HWSZ] = sb * inv;
}

extern "C" void kernel_launch(void* const* d_in, const int* in_sizes, int n_in,
                              void* d_out, int out_size, void* d_ws, size_t ws_size,
                              hipStream_t stream) {
    const float* x = (const float*)d_in[0];
    float* out = (float*)d_out;
    int total = in_sizes[0] / 3;          // N*H*W = 8*512*512
    int blocks = (total + 255) / 256;
    wavg_kernel<<<blocks, 256, 0, stream>>>(x, out, total);
}